// Round 8
// baseline (110.831 us; speedup 1.0000x reference)
//
#include <hip/hip_runtime.h>
#include <hip/hip_bf16.h>
#include <math.h>

// Problem dims (fixed by reference)
#define B_ 16
#define T_ 1024
#define C_ 768
#define H_ 64

typedef __attribute__((ext_vector_type(8))) short bf16x8;
typedef __attribute__((ext_vector_type(4))) float f32x4;

// fp32 -> bf16 (round-to-nearest-even)
__device__ __forceinline__ short f2bf(float f) {
  union { float f; unsigned u; } un;
  un.f = f;
  unsigned r = un.u + 0x7FFFu + ((un.u >> 16) & 1u);
  return (short)(r >> 16);
}

// ---------------------------------------------------------------------------
// Kernel 1: W prep in MFMA fragment order (unchanged).
// frag_id = ks*12 + ct (ks = k-step of 32, ct = col-tile 0..11, mat = ct>>2).
// ---------------------------------------------------------------------------
__global__ __launch_bounds__(256) void prep_w(
    const float* __restrict__ Wq, const float* __restrict__ Wk,
    const float* __restrict__ Wv, short* __restrict__ wfrag) {
  const int o = blockIdx.x * 256 + threadIdx.x;   // 0..147455
  const int j = o & 7;
  const int l = (o >> 3) & 63;
  const int fid = o >> 9;
  const int ct = fid % 12;
  const int ks = fid / 12;
  const int mat = ct >> 2;
  const int col = (ct & 3) * 16 + (l & 15);
  const int k = ks * 32 + (l >> 4) * 8 + j;
  const float* W = (mat == 0) ? Wq : (mat == 1) ? Wk : Wv;
  wfrag[o] = f2bf(W[(size_t)k * H_ + col]);
}

// ---------------------------------------------------------------------------
// Kernel 2: QKV projection. 256 thr = 4 waves; wave w = K-quarter (192 k,
// 6 chunks of BK=32). Triple-buffered x staging via global_load_lds
// (pre-swizzled source, XOR-swizzled ds_read), depth-2 prefetch, no barriers
// in the main loop. K-quarter partials merged via LDS atomicAdd (ds_add_f32)
// into a padded 16x196 pool. LDS total 37KB -> 3 blocks/CU (3 waves/SIMD).
// ---------------------------------------------------------------------------
#define QKV_LDSF 9280  // floats: staging 4w*3buf*512 = 6144; pool 16*196 = 3136

__global__ __launch_bounds__(256, 3) void qkv_gemm(
    const float* __restrict__ x, const short* __restrict__ wfrag,
    const float* __restrict__ bq, const float* __restrict__ bk,
    const float* __restrict__ bv, short* __restrict__ qkv) {
  __shared__ float lds[QKV_LDSF];
  const int rt = blockIdx.x;            // 16-row tile
  const int tid = threadIdx.x;
  const int w  = tid >> 6;              // wave = K-quarter
  const int l  = tid & 63;
  const int lo = l & 15, hi = l >> 4;

  // zero the merge pool, then barrier (before any atomics can happen)
  float* pool = lds + 6144;
  #pragma unroll
  for (int i = 0; i < 13; ++i) {
    const int idx = tid + i * 256;
    if (idx < 3136) pool[idx] = 0.f;
  }
  __syncthreads();

  float* stg = lds + w * 1536;          // 3 bufs x 512 floats (2KB each)
  const char* xb = (const char*)(x + (size_t)rt * 16 * C_ + w * 192);

  // stage chunk c (32 k-floats x 16 rows = 2KB): 2 global_load_lds.
  auto STAGE = [&](int buf, int c) {
    #pragma unroll
    for (int s = 0; s < 2; ++s) {
      const int row = s * 8 + (l >> 3);
      const char* src = xb + (size_t)row * (C_ * 4) + (size_t)c * 128
                        + (((l & 7) * 16) ^ ((row & 7) << 4));
      float* dst = stg + buf * 512 + s * 256;   // wave-uniform base
      __builtin_amdgcn_global_load_lds(
          (const __attribute__((address_space(1))) void*)src,
          (__attribute__((address_space(3))) void*)dst, 16, 0, 0);
    }
  };

  f32x4 acc[12];
  #pragma unroll
  for (int ct = 0; ct < 12; ++ct) acc[ct] = (f32x4){0.f, 0.f, 0.f, 0.f};

  STAGE(0, 0);
  STAGE(1, 1);

  #pragma unroll
  for (int c = 0; c < 6; ++c) {
    const int buf = c % 3;
    __builtin_amdgcn_sched_barrier(0);
    // ---- W-frag loads for this chunk (12 coalesced 16B/lane)
    bf16x8 wf[12];
    const int ks = w * 6 + c;
    #pragma unroll
    for (int ct = 0; ct < 12; ++ct)
      wf[ct] = *(const bf16x8*)(wfrag + ((size_t)(ks * 12 + ct) << 9) + l * 8);
    __builtin_amdgcn_sched_barrier(0);
    // ---- stage chunk c+2 (depth-2 prefetch)
    if (c < 4) STAGE((c + 2) % 3, c + 2);
    __builtin_amdgcn_sched_barrier(0);
    // ---- wait for THIS chunk's stage only (exact in-order ladder:
    // ops issued after S(c): c=0:16, c=1..3:28, c=4:26, c=5:24)
    if (c == 0)      { asm volatile("s_waitcnt vmcnt(16)" ::: "memory"); }
    else if (c < 4)  { asm volatile("s_waitcnt vmcnt(28)" ::: "memory"); }
    else if (c == 4) { asm volatile("s_waitcnt vmcnt(26)" ::: "memory"); }
    else             { asm volatile("s_waitcnt vmcnt(24)" ::: "memory"); }
    __builtin_amdgcn_sched_barrier(0);
    // ---- A-frag from LDS (XOR-swz) + cvt + 12 MFMAs
    bf16x8 af;
    {
      const char* rowbase = (const char*)(stg + buf * 512)
                            + (lo >> 3) * 1024 + (lo & 7) * 128;
      const int sw = (lo & 7) << 4;
      f32x4 x0 = *(const f32x4*)(rowbase + ((hi * 32)      ^ sw));
      f32x4 x1 = *(const f32x4*)(rowbase + ((hi * 32 + 16) ^ sw));
      #pragma unroll
      for (int j = 0; j < 4; ++j) { af[j] = f2bf(x0[j]); af[4 + j] = f2bf(x1[j]); }
    }
    __builtin_amdgcn_s_setprio(1);
    #pragma unroll
    for (int ct = 0; ct < 12; ++ct)
      acc[ct] = __builtin_amdgcn_mfma_f32_16x16x32_bf16(af, wf[ct], acc[ct], 0, 0, 0);
    __builtin_amdgcn_s_setprio(0);
  }

  // ---- merge K-quarters: LDS atomic add into padded pool [16][196]
  #pragma unroll
  for (int ct = 0; ct < 12; ++ct)
    #pragma unroll
    for (int r = 0; r < 4; ++r)
      atomicAdd(&pool[(hi * 4 + r) * 196 + ct * 16 + lo], acc[ct][r]);
  __syncthreads();

  // ---- epilogue (first 128 threads): row = t>>3, 24 cols each
  if (tid < 128) {
    const int row = tid >> 3;
    const int c0 = (tid & 7) * 24;
    bf16x8 o0, o1, o2;
    #pragma unroll
    for (int j = 0; j < 24; ++j) {
      const int col = c0 + j;
      float s = pool[row * 196 + col];
      const int mat = col >> 6;
      const float* bb = (mat == 0) ? bq : (mat == 1) ? bk : bv;
      s += bb[col & 63];
      const short v = f2bf(s);
      if (j < 8) o0[j] = v; else if (j < 16) o1[j - 8] = v; else o2[j - 16] = v;
    }
    short* op = qkv + ((size_t)(rt * 16 + row)) * 192 + c0;
    *(bf16x8*)(op)      = o0;
    *(bf16x8*)(op + 8)  = o1;
    *(bf16x8*)(op + 16) = o2;
  }
}

// ---------------------------------------------------------------------------
// Kernel 3: V transpose — Vt[b][n][t] = v[b][t][n] (bf16), via LDS tiles.
// (unchanged; reads v at qkv[row][128..192), stride 192)
// ---------------------------------------------------------------------------
__global__ __launch_bounds__(256) void vtrans(const short* __restrict__ qkv,
                                              short* __restrict__ vt) {
  __shared__ short tile[64][66];
  const int b = blockIdx.y;
  const int tb = blockIdx.x * 64;
  const int tid = threadIdx.x;

  {
    const int tt = tid >> 2, c = (tid & 3) * 16;
    const short* src = qkv + (size_t)(b * T_ + tb + tt) * 192 + 128 + c;
    bf16x8 v0 = *(const bf16x8*)(src);
    bf16x8 v1 = *(const bf16x8*)(src + 8);
    #pragma unroll
    for (int j = 0; j < 8; ++j) { tile[tt][c + j] = v0[j]; tile[tt][c + 8 + j] = v1[j]; }
  }
  __syncthreads();
  {
    const int n = tid >> 2, toff = (tid & 3) * 16;
    short* dst = vt + ((size_t)(b * H_ + n)) * T_ + tb + toff;
    bf16x8 o0, o1;
    #pragma unroll
    for (int j = 0; j < 8; ++j) { o0[j] = tile[toff + j][n]; o1[j] = tile[toff + 8 + j][n]; }
    *(bf16x8*)(dst) = o0;
    *(bf16x8*)(dst + 8) = o1;
  }
}

// ---------------------------------------------------------------------------
// Kernel 4: flash attention, 4-way KV-split, swapped QK^T, XCD-aware grid,
// hoisted K/V loads. NEW: defer-max (T13, THR=8 in log2 units) — skip the
// corr/rescale path when the tile max doesn't grow (wave-uniform __all).
// ---------------------------------------------------------------------------
#define SCALE_LOG2E 0.18033688011114382f  // 0.125 * log2(e)

__global__ __launch_bounds__(256) void flash(
    const short* __restrict__ qkv, const short* __restrict__ vt,
    float* __restrict__ out) {
  __shared__ __align__(16) short p_lds[4][16][72];
  __shared__ float o_sh[4][16][64];
  __shared__ float ml_sh[4][2][16];

  // XCD swizzle: wgid = ((63-qt) + 64*(b>>3))*8 + (b&7)
  const int wgid = blockIdx.x;
  const int kk = wgid >> 3;
  const int qt = 63 - (kk & 63);            // big tiles dispatched first
  const int b  = (wgid & 7) + 8 * (kk >> 6);

  const int w = threadIdx.x >> 6;
  const int l = threadIdx.x & 63;
  const int lo = l & 15, hi = l >> 4;

  const int dtile = qt >> 2;
  const int ntot = dtile + 1;
  const int span = (ntot + 3) >> 2;
  const int kv0 = w * span;
  const int kv1 = min(ntot, kv0 + span);
  const int qr = qt & 3;

  const short* qrow = qkv + (size_t)(b * T_ + qt * 16 + lo) * 192;  // q at +0
  bf16x8 qf0 = *(const bf16x8*)(qrow + hi * 8);
  bf16x8 qf1 = *(const bf16x8*)(qrow + 32 + hi * 8);

  float m_l = -1e30f;   // running max for q-row `lo` (log2 units)
  float l_l = 0.f;      // running denom for q-row `lo`
  f32x4 oacc[4];
  #pragma unroll
  for (int dt = 0; dt < 4; ++dt) oacc[dt] = (f32x4){0.f, 0.f, 0.f, 0.f};

  for (int kvt = kv0; kvt < kv1; ++kvt) {
    const bool diag = (kvt == dtile);
    const int nct = diag ? (qr + 1) : 4;

    // ---- batch-issue ALL K and V loads for this tile
    bf16x8 kf[8], vf[8];
    #pragma unroll
    for (int ct = 0; ct < 4; ++ct) {
      const short* krow = qkv + (size_t)(b * T_ + kvt * 64 + ct * 16 + lo) * 192 + 64;
      kf[2 * ct]     = *(const bf16x8*)(krow + hi * 8);
      kf[2 * ct + 1] = *(const bf16x8*)(krow + 32 + hi * 8);
    }
    #pragma unroll
    for (int dt = 0; dt < 4; ++dt) {
      const short* vrow = vt + (size_t)(b * H_ + dt * 16 + lo) * T_ + kvt * 64;
      vf[2 * dt]     = *(const bf16x8*)(vrow + hi * 8);
      vf[2 * dt + 1] = *(const bf16x8*)(vrow + 32 + hi * 8);
    }

    // S^T tile: sv[ct][r] = S[key = ct*16 + hi*4 + r][q-row = lo]
    f32x4 sv[4];
    #pragma unroll
    for (int ct = 0; ct < 4; ++ct) sv[ct] = (f32x4){0.f, 0.f, 0.f, 0.f};
    __builtin_amdgcn_s_setprio(1);
    #pragma unroll
    for (int ct = 0; ct < 4; ++ct) {
      if (ct < nct) {
        sv[ct] = __builtin_amdgcn_mfma_f32_16x16x32_bf16(kf[2 * ct], qf0, sv[ct], 0, 0, 0);
        sv[ct] = __builtin_amdgcn_mfma_f32_16x16x32_bf16(kf[2 * ct + 1], qf1, sv[ct], 0, 0, 0);
      }
    }
    __builtin_amdgcn_s_setprio(0);

    // scale (log2 units) + causal mask
    #pragma unroll
    for (int ct = 0; ct < 4; ++ct) {
      #pragma unroll
      for (int r = 0; r < 4; ++r) {
        float s = (ct < nct) ? sv[ct][r] * SCALE_LOG2E : -1e30f;
        if (diag && ct == qr && (hi * 4 + r) > lo) s = -1e30f;
        sv[ct][r] = s;
      }
    }

    // tile max for row `lo` (16 keys local; partners via xor 16/32)
    float tmax = sv[0][0];
    #pragma unroll
    for (int ct = 0; ct < 4; ++ct)
      #pragma unroll
      for (int r = 0; r < 4; ++r) tmax = fmaxf(tmax, sv[ct][r]);
    tmax = fmaxf(tmax, __shfl_xor(tmax, 16));
    tmax = fmaxf(tmax, __shfl_xor(tmax, 32));

    // defer-max: only rescale when some row's max grew by > 8 (log2 units)
    if (!__all(tmax - m_l <= 8.0f)) {
      const float mn = fmaxf(m_l, tmax);
      const float corr = exp2f(m_l - mn);
      m_l = mn;
      l_l *= corr;
      #pragma unroll
      for (int r = 0; r < 4; ++r) {
        const float cr = __shfl(corr, hi * 4 + r);
        #pragma unroll
        for (int dt = 0; dt < 4; ++dt) oacc[dt][r] *= cr;
      }
    }

    float psum = 0.f;
    #pragma unroll
    for (int ct = 0; ct < 4; ++ct) {
      #pragma unroll
      for (int r = 0; r < 4; ++r) {
        float p = exp2f(sv[ct][r] - m_l);
        sv[ct][r] = p;
        psum += p;
      }
    }
    psum += __shfl_xor(psum, 16);
    psum += __shfl_xor(psum, 32);
    l_l += psum;

    // P -> bf16 (cvt_pk pairs), packed 8B write
    #pragma unroll
    for (int ct = 0; ct < 4; ++ct) {
      __hip_bfloat162 p01 = __float22bfloat162_rn(float2{sv[ct][0], sv[ct][1]});
      __hip_bfloat162 p23 = __float22bfloat162_rn(float2{sv[ct][2], sv[ct][3]});
      uint2 pk;
      pk.x = *reinterpret_cast<unsigned*>(&p01);
      pk.y = *reinterpret_cast<unsigned*>(&p23);
      *reinterpret_cast<uint2*>(&p_lds[w][lo][ct * 16 + hi * 4]) = pk;
    }

    // O += P V
    bf16x8 pa0 = *(const bf16x8*)(&p_lds[w][lo][hi * 8]);
    bf16x8 pa1 = *(const bf16x8*)(&p_lds[w][lo][32 + hi * 8]);
    __builtin_amdgcn_s_setprio(1);
    #pragma unroll
    for (int dt = 0; dt < 4; ++dt) {
      oacc[dt] = __builtin_amdgcn_mfma_f32_16x16x32_bf16(pa0, vf[2 * dt], oacc[dt], 0, 0, 0);
      oacc[dt] = __builtin_amdgcn_mfma_f32_16x16x32_bf16(pa1, vf[2 * dt + 1], oacc[dt], 0, 0, 0);
    }
    __builtin_amdgcn_s_setprio(0);
  }

  // publish partials
  #pragma unroll
  for (int dt = 0; dt < 4; ++dt)
    #pragma unroll
    for (int r = 0; r < 4; ++r)
      o_sh[w][hi * 4 + r][dt * 16 + lo] = oacc[dt][r];
  if (hi == 0) {
    ml_sh[w][0][lo] = m_l;
    ml_sh[w][1][lo] = l_l;
  }
  __syncthreads();

  // merge (log2 units)
  {
    const int row = threadIdx.x >> 4;
    const int c0 = (threadIdx.x & 15) * 4;
    float M = fmaxf(fmaxf(ml_sh[0][0][row], ml_sh[1][0][row]),
                    fmaxf(ml_sh[2][0][row], ml_sh[3][0][row]));
    float e[4];
    float L = 0.f;
    #pragma unroll
    for (int w2 = 0; w2 < 4; ++w2) {
      e[w2] = exp2f(ml_sh[w2][0][row] - M);
      L += ml_sh[w2][1][row] * e[w2];
    }
    f32x4 o;
    #pragma unroll
    for (int j = 0; j < 4; ++j) {
      float O = 0.f;
      #pragma unroll
      for (int w2 = 0; w2 < 4; ++w2) O += e[w2] * o_sh[w2][row][c0 + j];
      o[j] = O / L;
    }
    *(f32x4*)(out + (size_t)(b * T_ + qt * 16 + row) * H_ + c0) = o;
  }
}

// ---------------------------------------------------------------------------
extern "C" void kernel_launch(void* const* d_in, const int* in_sizes, int n_in,
                              void* d_out, int out_size, void* d_ws, size_t ws_size,
                              hipStream_t stream) {
  const float* x  = (const float*)d_in[0];
  const float* Wq = (const float*)d_in[1];
  const float* bq = (const float*)d_in[2];
  const float* Wk = (const float*)d_in[3];
  const float* bk = (const float*)d_in[4];
  const float* Wv = (const float*)d_in[5];
  const float* bv = (const float*)d_in[6];
  float* out = (float*)d_out;

  // workspace layout (shorts): wfrag | qkv(interleaved, stride 192) | vt
  short* wfrag = (short*)d_ws;
  short* qkv = wfrag + (size_t)3 * H_ * C_;          // 147456
  short* vtb = qkv + (size_t)B_ * T_ * 192;          // +3145728

  prep_w<<<dim3(576), dim3(256), 0, stream>>>(Wq, Wk, Wv, wfrag);
  qkv_gemm<<<dim3(1024), dim3(256), 0, stream>>>(x, wfrag, bq, bk, bv, qkv);
  vtrans<<<dim3(T_ / 64, B_), dim3(256), 0, stream>>>(qkv, vtb);
  flash<<<dim3(1024), dim3(256), 0, stream>>>(qkv, vtb, out);
}

// Round 9
// 51.849 us; speedup vs baseline: 2.1376x; 2.1376x over previous
//
#include <hip/hip_runtime.h>
#include <hip/hip_bf16.h>
#include <math.h>

// Problem dims (fixed by reference)
#define B_ 16
#define T_ 1024
#define C_ 768
#define H_ 64

typedef __attribute__((ext_vector_type(8))) short bf16x8;
typedef __attribute__((ext_vector_type(4))) float f32x4;

// fp32 -> bf16 (round-to-nearest-even)
__device__ __forceinline__ short f2bf(float f) {
  union { float f; unsigned u; } un;
  un.f = f;
  unsigned r = un.u + 0x7FFFu + ((un.u >> 16) & 1u);
  return (short)(r >> 16);
}

// ---------------------------------------------------------------------------
// Kernel 1: W prep in MFMA fragment order (unchanged).
// ---------------------------------------------------------------------------
__global__ __launch_bounds__(256) void prep_w(
    const float* __restrict__ Wq, const float* __restrict__ Wk,
    const float* __restrict__ Wv, short* __restrict__ wfrag) {
  const int o = blockIdx.x * 256 + threadIdx.x;   // 0..147455
  const int j = o & 7;
  const int l = (o >> 3) & 63;
  const int fid = o >> 9;
  const int ct = fid % 12;
  const int ks = fid / 12;
  const int mat = ct >> 2;
  const int col = (ct & 3) * 16 + (l & 15);
  const int k = ks * 32 + (l >> 4) * 8 + j;
  const float* W = (mat == 0) ? Wq : (mat == 1) ? Wk : Wv;
  wfrag[o] = f2bf(W[(size_t)k * H_ + col]);
}

// ---------------------------------------------------------------------------
// Kernel 2: QKV projection — ROUND-7-BENCHED STRUCTURE RESTORED VERBATIM.
// 2 waves = 2 K-halves per 16-row tile, BK=64 chunks, TRIPLE-buffered x
// staging (depth-2 prefetch) via global_load_lds, vmcnt ladder 32/28/24.
// ---------------------------------------------------------------------------
#define QKV_LDSF 6400  // floats: staging 2w*3*1024=6144; pool 2*16*196=6272

__global__ __launch_bounds__(128, 2) void qkv_gemm(
    const float* __restrict__ x, const short* __restrict__ wfrag,
    const float* __restrict__ bq, const float* __restrict__ bk,
    const float* __restrict__ bv, short* __restrict__ qkv) {
  __shared__ float lds[QKV_LDSF];
  const int rt = blockIdx.x;            // 16-row tile
  const int w  = threadIdx.x >> 6;      // wave = K-half
  const int l  = threadIdx.x & 63;
  const int lo = l & 15, hi = l >> 4;
  const int kh = w;

  float* stg = lds + w * 3072;          // 3 bufs x 1024 floats (4KB each)
  const char* xb = (const char*)(x + (size_t)rt * 16 * C_ + kh * 384);

  auto STAGE = [&](int buf, int c) {
    #pragma unroll
    for (int s = 0; s < 4; ++s) {
      const int r = s * 4 + hi;
      const char* src = xb + (size_t)r * (C_ * 4) + (size_t)c * 256
                        + ((lo * 16) ^ ((r & 7) << 4));
      float* dst = stg + buf * 1024 + s * 256;  // wave-uniform base
      __builtin_amdgcn_global_load_lds(
          (const __attribute__((address_space(1))) void*)src,
          (__attribute__((address_space(3))) void*)dst, 16, 0, 0);
    }
  };

  f32x4 acc[12];
  #pragma unroll
  for (int ct = 0; ct < 12; ++ct) acc[ct] = (f32x4){0.f, 0.f, 0.f, 0.f};

  STAGE(0, 0);
  STAGE(1, 1);

  #pragma unroll
  for (int c = 0; c < 6; ++c) {
    const int buf = c % 3;
    __builtin_amdgcn_sched_barrier(0);
    // ---- W-frag loads for this chunk (24 coalesced 16B/lane)
    bf16x8 wf0[12], wf1[12];
    const int ksb = kh * 12 + c * 2;
    #pragma unroll
    for (int ct = 0; ct < 12; ++ct) {
      wf0[ct] = *(const bf16x8*)(wfrag + ((size_t)(ksb * 12 + ct) << 9) + l * 8);
      wf1[ct] = *(const bf16x8*)(wfrag + ((size_t)((ksb + 1) * 12 + ct) << 9) + l * 8);
    }
    __builtin_amdgcn_sched_barrier(0);
    // ---- stage chunk c+2 (depth-2 prefetch)
    if (c < 4) STAGE((c + 2) % 3, c + 2);
    __builtin_amdgcn_sched_barrier(0);
    // ---- wait for THIS chunk's stage only
    if (c < 4)      { asm volatile("s_waitcnt vmcnt(32)" ::: "memory"); }
    else if (c < 5) { asm volatile("s_waitcnt vmcnt(28)" ::: "memory"); }
    else            { asm volatile("s_waitcnt vmcnt(24)" ::: "memory"); }
    __builtin_amdgcn_sched_barrier(0);
    // ---- A-frags from LDS (XOR-swz) + cvt + 24 MFMAs
    bf16x8 af0, af1;
    {
      const char* rp = (const char*)(stg + buf * 1024) + lo * 256;
      const int sw = (lo & 7) << 4;
      f32x4 x0 = *(const f32x4*)(rp + ((hi * 32)       ^ sw));
      f32x4 x1 = *(const f32x4*)(rp + ((hi * 32 + 16)  ^ sw));
      f32x4 x2 = *(const f32x4*)(rp + ((128 + hi * 32)      ^ sw));
      f32x4 x3 = *(const f32x4*)(rp + ((128 + hi * 32 + 16) ^ sw));
      #pragma unroll
      for (int j = 0; j < 4; ++j) {
        af0[j] = f2bf(x0[j]); af0[4 + j] = f2bf(x1[j]);
        af1[j] = f2bf(x2[j]); af1[4 + j] = f2bf(x3[j]);
      }
    }
    __builtin_amdgcn_s_setprio(1);
    #pragma unroll
    for (int ct = 0; ct < 12; ++ct)
      acc[ct] = __builtin_amdgcn_mfma_f32_16x16x32_bf16(af0, wf0[ct], acc[ct], 0, 0, 0);
    #pragma unroll
    for (int ct = 0; ct < 12; ++ct)
      acc[ct] = __builtin_amdgcn_mfma_f32_16x16x32_bf16(af1, wf1[ct], acc[ct], 0, 0, 0);
    __builtin_amdgcn_s_setprio(0);
  }

  // ---- merge K-halves through LDS (pool overlaps staging; barrier first)
  __syncthreads();
  #pragma unroll
  for (int ct = 0; ct < 12; ++ct)
    #pragma unroll
    for (int r = 0; r < 4; ++r)
      lds[w * 3136 + (hi * 4 + r) * 196 + ct * 16 + lo] = acc[ct][r];
  __syncthreads();

  {
    const int row = threadIdx.x >> 3;          // 0..15
    const int c0 = (threadIdx.x & 7) * 24;     // 0..168
    bf16x8 o0, o1, o2;
    #pragma unroll
    for (int j = 0; j < 24; ++j) {
      const int col = c0 + j;
      float s = lds[row * 196 + col] + lds[3136 + row * 196 + col];
      const int mat = col >> 6;
      const float* bb = (mat == 0) ? bq : (mat == 1) ? bk : bv;
      s += bb[col & 63];
      const short v = f2bf(s);
      if (j < 8) o0[j] = v; else if (j < 16) o1[j - 8] = v; else o2[j - 16] = v;
    }
    short* op = qkv + ((size_t)(rt * 16 + row)) * 192 + c0;
    *(bf16x8*)(op)      = o0;
    *(bf16x8*)(op + 8)  = o1;
    *(bf16x8*)(op + 16) = o2;
  }
}

// ---------------------------------------------------------------------------
// Kernel 3: V transpose — Vt[b][n][t] = v[b][t][n] (bf16), via LDS tiles.
// ---------------------------------------------------------------------------
__global__ __launch_bounds__(256) void vtrans(const short* __restrict__ qkv,
                                              short* __restrict__ vt) {
  __shared__ short tile[64][66];
  const int b = blockIdx.y;
  const int tb = blockIdx.x * 64;
  const int tid = threadIdx.x;

  {
    const int tt = tid >> 2, c = (tid & 3) * 16;
    const short* src = qkv + (size_t)(b * T_ + tb + tt) * 192 + 128 + c;
    bf16x8 v0 = *(const bf16x8*)(src);
    bf16x8 v1 = *(const bf16x8*)(src + 8);
    #pragma unroll
    for (int j = 0; j < 8; ++j) { tile[tt][c + j] = v0[j]; tile[tt][c + 8 + j] = v1[j]; }
  }
  __syncthreads();
  {
    const int n = tid >> 2, toff = (tid & 3) * 16;
    short* dst = vt + ((size_t)(b * H_ + n)) * T_ + tb + toff;
    bf16x8 o0, o1;
    #pragma unroll
    for (int j = 0; j < 8; ++j) { o0[j] = tile[toff + j][n]; o1[j] = tile[toff + 8 + j][n]; }
    *(bf16x8*)(dst) = o0;
    *(bf16x8*)(dst + 8) = o1;
  }
}

// ---------------------------------------------------------------------------
// Kernel 4: flash attention, PAIRED q-tiles. Block handles q-tiles 2i,2i+1
// (identical KV range: odd qt never opens a new KV tile) so one set of K/V
// loads feeds both tiles' QK^T and PV — halves L2 traffic per MFMA.
// 4-way KV-split, swapped QK^T, XCD-aware grid, defer-max.
// ---------------------------------------------------------------------------
#define SCALE_LOG2E 0.18033688011114382f  // 0.125 * log2(e)

__global__ __launch_bounds__(256) void flash(
    const short* __restrict__ qkv, const short* __restrict__ vt,
    float* __restrict__ out) {
  __shared__ __align__(16) short p_lds[4][2][16][72];
  __shared__ float o_sh[4][16][64];
  __shared__ float ml_sh[4][2][2][16];  // [wave][tile][m|l][row]

  // XCD swizzle: 512 blocks; wgid = ((31-qp) + 32*(b>>3))*8 + (b&7)
  const int wgid = blockIdx.x;
  const int kk = wgid >> 3;
  const int qp = 31 - (kk & 31);            // big pairs dispatched first
  const int b  = (wgid & 7) + 8 * (kk >> 5);

  const int w = threadIdx.x >> 6;
  const int l = threadIdx.x & 63;
  const int lo = l & 15, hi = l >> 4;
  const int off = hi * 4;                   // key sub-offset base

  const int qt0 = 2 * qp, qt1 = 2 * qp + 1;
  const int dtile = qt0 >> 2;               // == qt1 >> 2 (qt1 odd)
  const int ntot = dtile + 1;
  const int span = (ntot + 3) >> 2;
  const int kv0 = w * span;
  const int kv1 = min(ntot, kv0 + span);
  const int qr0 = qt0 & 3, qr1 = qr0 + 1;

  const short* qrowA = qkv + (size_t)(b * T_ + qt0 * 16 + lo) * 192;
  bf16x8 qA0 = *(const bf16x8*)(qrowA + hi * 8);
  bf16x8 qA1 = *(const bf16x8*)(qrowA + 32 + hi * 8);
  const short* qrowB = qkv + (size_t)(b * T_ + qt1 * 16 + lo) * 192;
  bf16x8 qB0 = *(const bf16x8*)(qrowB + hi * 8);
  bf16x8 qB1 = *(const bf16x8*)(qrowB + 32 + hi * 8);

  float mA = -1e30f, lsA = 0.f;
  float mB = -1e30f, lsB = 0.f;
  f32x4 oA[4], oB[4];
  #pragma unroll
  for (int dt = 0; dt < 4; ++dt) {
    oA[dt] = (f32x4){0.f, 0.f, 0.f, 0.f};
    oB[dt] = (f32x4){0.f, 0.f, 0.f, 0.f};
  }

  for (int kvt = kv0; kvt < kv1; ++kvt) {
    const bool diag = (kvt == dtile);
    const int nctA = diag ? (qr0 + 1) : 4;
    const int nctB = diag ? (qr1 + 1) : 4;

    // ---- shared K/V loads for this tile (always in-bounds)
    bf16x8 kf[8], vf[8];
    #pragma unroll
    for (int ct = 0; ct < 4; ++ct) {
      const short* krow = qkv + (size_t)(b * T_ + kvt * 64 + ct * 16 + lo) * 192 + 64;
      kf[2 * ct]     = *(const bf16x8*)(krow + hi * 8);
      kf[2 * ct + 1] = *(const bf16x8*)(krow + 32 + hi * 8);
    }
    #pragma unroll
    for (int dt = 0; dt < 4; ++dt) {
      const short* vrow = vt + (size_t)(b * H_ + dt * 16 + lo) * T_ + kvt * 64;
      vf[2 * dt]     = *(const bf16x8*)(vrow + hi * 8);
      vf[2 * dt + 1] = *(const bf16x8*)(vrow + 32 + hi * 8);
    }

    // ---- S^T for both tiles: sv[ct][r] = S[key=ct*16+off+r][q-row=lo]
    f32x4 svA[4], svB[4];
    #pragma unroll
    for (int ct = 0; ct < 4; ++ct) {
      svA[ct] = (f32x4){0.f, 0.f, 0.f, 0.f};
      svB[ct] = (f32x4){0.f, 0.f, 0.f, 0.f};
    }
    __builtin_amdgcn_s_setprio(1);
    #pragma unroll
    for (int ct = 0; ct < 4; ++ct) {
      if (ct < nctA) {
        svA[ct] = __builtin_amdgcn_mfma_f32_16x16x32_bf16(kf[2 * ct], qA0, svA[ct], 0, 0, 0);
        svA[ct] = __builtin_amdgcn_mfma_f32_16x16x32_bf16(kf[2 * ct + 1], qA1, svA[ct], 0, 0, 0);
      }
      if (ct < nctB) {
        svB[ct] = __builtin_amdgcn_mfma_f32_16x16x32_bf16(kf[2 * ct], qB0, svB[ct], 0, 0, 0);
        svB[ct] = __builtin_amdgcn_mfma_f32_16x16x32_bf16(kf[2 * ct + 1], qB1, svB[ct], 0, 0, 0);
      }
    }
    __builtin_amdgcn_s_setprio(0);

    // ---- scale (log2 units) + causal mask
    #pragma unroll
    for (int ct = 0; ct < 4; ++ct) {
      #pragma unroll
      for (int r = 0; r < 4; ++r) {
        float sA = (ct < nctA) ? svA[ct][r] * SCALE_LOG2E : -1e30f;
        if (diag && ct == qr0 && (off + r) > lo) sA = -1e30f;
        svA[ct][r] = sA;
        float sB = (ct < nctB) ? svB[ct][r] * SCALE_LOG2E : -1e30f;
        if (diag && ct == qr1 && (off + r) > lo) sB = -1e30f;
        svB[ct][r] = sB;
      }
    }

    // ---- online softmax tile A
    {
      float tmax = svA[0][0];
      #pragma unroll
      for (int ct = 0; ct < 4; ++ct)
        #pragma unroll
        for (int r = 0; r < 4; ++r) tmax = fmaxf(tmax, svA[ct][r]);
      tmax = fmaxf(tmax, __shfl_xor(tmax, 16));
      tmax = fmaxf(tmax, __shfl_xor(tmax, 32));
      if (!__all(tmax - mA <= 8.0f)) {
        const float mn = fmaxf(mA, tmax);
        const float corr = exp2f(mA - mn);
        mA = mn;
        lsA *= corr;
        #pragma unroll
        for (int r = 0; r < 4; ++r) {
          const float cr = __shfl(corr, off + r);
          #pragma unroll
          for (int dt = 0; dt < 4; ++dt) oA[dt][r] *= cr;
        }
      }
      float psum = 0.f;
      #pragma unroll
      for (int ct = 0; ct < 4; ++ct) {
        #pragma unroll
        for (int r = 0; r < 4; ++r) {
          float p = exp2f(svA[ct][r] - mA);
          svA[ct][r] = p;
          psum += p;
        }
      }
      psum += __shfl_xor(psum, 16);
      psum += __shfl_xor(psum, 32);
      lsA += psum;
      #pragma unroll
      for (int ct = 0; ct < 4; ++ct) {
        __hip_bfloat162 p01 = __float22bfloat162_rn(float2{svA[ct][0], svA[ct][1]});
        __hip_bfloat162 p23 = __float22bfloat162_rn(float2{svA[ct][2], svA[ct][3]});
        uint2 pk;
        pk.x = *reinterpret_cast<unsigned*>(&p01);
        pk.y = *reinterpret_cast<unsigned*>(&p23);
        *reinterpret_cast<uint2*>(&p_lds[w][0][lo][ct * 16 + off]) = pk;
      }
    }
    // ---- online softmax tile B
    {
      float tmax = svB[0][0];
      #pragma unroll
      for (int ct = 0; ct < 4; ++ct)
        #pragma unroll
        for (int r = 0; r < 4; ++r) tmax = fmaxf(tmax, svB[ct][r]);
      tmax = fmaxf(tmax, __shfl_xor(tmax, 16));
      tmax = fmaxf(tmax, __shfl_xor(tmax, 32));
      if (!__all(tmax - mB <= 8.0f)) {
        const float mn = fmaxf(mB, tmax);
        const float corr = exp2f(mB - mn);
        mB = mn;
        lsB *= corr;
        #pragma unroll
        for (int r = 0; r < 4; ++r) {
          const float cr = __shfl(corr, off + r);
          #pragma unroll
          for (int dt = 0; dt < 4; ++dt) oB[dt][r] *= cr;
        }
      }
      float psum = 0.f;
      #pragma unroll
      for (int ct = 0; ct < 4; ++ct) {
        #pragma unroll
        for (int r = 0; r < 4; ++r) {
          float p = exp2f(svB[ct][r] - mB);
          svB[ct][r] = p;
          psum += p;
        }
      }
      psum += __shfl_xor(psum, 16);
      psum += __shfl_xor(psum, 32);
      lsB += psum;
      #pragma unroll
      for (int ct = 0; ct < 4; ++ct) {
        __hip_bfloat162 p01 = __float22bfloat162_rn(float2{svB[ct][0], svB[ct][1]});
        __hip_bfloat162 p23 = __float22bfloat162_rn(float2{svB[ct][2], svB[ct][3]});
        uint2 pk;
        pk.x = *reinterpret_cast<unsigned*>(&p01);
        pk.y = *reinterpret_cast<unsigned*>(&p23);
        *reinterpret_cast<uint2*>(&p_lds[w][1][lo][ct * 16 + off]) = pk;
      }
    }

    // ---- PV for both tiles (shared vf)
    bf16x8 paA0 = *(const bf16x8*)(&p_lds[w][0][lo][hi * 8]);
    bf16x8 paA1 = *(const bf16x8*)(&p_lds[w][0][lo][32 + hi * 8]);
    bf16x8 paB0 = *(const bf16x8*)(&p_lds[w][1][lo][hi * 8]);
    bf16x8 paB1 = *(const bf16x8*)(&p_lds[w][1][lo][32 + hi * 8]);
    __builtin_amdgcn_s_setprio(1);
    #pragma unroll
    for (int dt = 0; dt < 4; ++dt) {
      oA[dt] = __builtin_amdgcn_mfma_f32_16x16x32_bf16(paA0, vf[2 * dt], oA[dt], 0, 0, 0);
      oA[dt] = __builtin_amdgcn_mfma_f32_16x16x32_bf16(paA1, vf[2 * dt + 1], oA[dt], 0, 0, 0);
      oB[dt] = __builtin_amdgcn_mfma_f32_16x16x32_bf16(paB0, vf[2 * dt], oB[dt], 0, 0, 0);
      oB[dt] = __builtin_amdgcn_mfma_f32_16x16x32_bf16(paB1, vf[2 * dt + 1], oB[dt], 0, 0, 0);
    }
    __builtin_amdgcn_s_setprio(0);
  }

  // ---- publish m/l for both tiles
  if (hi == 0) {
    ml_sh[w][0][0][lo] = mA;  ml_sh[w][0][1][lo] = lsA;
    ml_sh[w][1][0][lo] = mB;  ml_sh[w][1][1][lo] = lsB;
  }

  // ---- merge + write tile A, then tile B (o_sh reused)
  #pragma unroll
  for (int dt = 0; dt < 4; ++dt)
    #pragma unroll
    for (int r = 0; r < 4; ++r)
      o_sh[w][off + r][dt * 16 + lo] = oA[dt][r];
  __syncthreads();
  {
    const int row = threadIdx.x >> 4;
    const int c0 = (threadIdx.x & 15) * 4;
    float M = fmaxf(fmaxf(ml_sh[0][0][0][row], ml_sh[1][0][0][row]),
                    fmaxf(ml_sh[2][0][0][row], ml_sh[3][0][0][row]));
    float e[4];
    float L = 0.f;
    #pragma unroll
    for (int w2 = 0; w2 < 4; ++w2) {
      e[w2] = exp2f(ml_sh[w2][0][0][row] - M);
      L += ml_sh[w2][0][1][row] * e[w2];
    }
    f32x4 o;
    #pragma unroll
    for (int j = 0; j < 4; ++j) {
      float O = 0.f;
      #pragma unroll
      for (int w2 = 0; w2 < 4; ++w2) O += e[w2] * o_sh[w2][row][c0 + j];
      o[j] = O / L;
    }
    *(f32x4*)(out + (size_t)(b * T_ + qt0 * 16 + row) * H_ + c0) = o;
  }
  __syncthreads();
  #pragma unroll
  for (int dt = 0; dt < 4; ++dt)
    #pragma unroll
    for (int r = 0; r < 4; ++r)
      o_sh[w][off + r][dt * 16 + lo] = oB[dt][r];
  __syncthreads();
  {
    const int row = threadIdx.x >> 4;
    const int c0 = (threadIdx.x & 15) * 4;
    float M = fmaxf(fmaxf(ml_sh[0][1][0][row], ml_sh[1][1][0][row]),
                    fmaxf(ml_sh[2][1][0][row], ml_sh[3][1][0][row]));
    float e[4];
    float L = 0.f;
    #pragma unroll
    for (int w2 = 0; w2 < 4; ++w2) {
      e[w2] = exp2f(ml_sh[w2][1][0][row] - M);
      L += ml_sh[w2][1][1][row] * e[w2];
    }
    f32x4 o;
    #pragma unroll
    for (int j = 0; j < 4; ++j) {
      float O = 0.f;
      #pragma unroll
      for (int w2 = 0; w2 < 4; ++w2) O += e[w2] * o_sh[w2][row][c0 + j];
      o[j] = O / L;
    }
    *(f32x4*)(out + (size_t)(b * T_ + qt1 * 16 + row) * H_ + c0) = o;
  }
}

// ---------------------------------------------------------------------------
extern "C" void kernel_launch(void* const* d_in, const int* in_sizes, int n_in,
                              void* d_out, int out_size, void* d_ws, size_t ws_size,
                              hipStream_t stream) {
  const float* x  = (const float*)d_in[0];
  const float* Wq = (const float*)d_in[1];
  const float* bq = (const float*)d_in[2];
  const float* Wk = (const float*)d_in[3];
  const float* bk = (const float*)d_in[4];
  const float* Wv = (const float*)d_in[5];
  const float* bv = (const float*)d_in[6];
  float* out = (float*)d_out;

  // workspace layout (shorts): wfrag | qkv(interleaved, stride 192) | vt
  short* wfrag = (short*)d_ws;
  short* qkv = wfrag + (size_t)3 * H_ * C_;          // 147456
  short* vtb = qkv + (size_t)B_ * T_ * 192;          // +3145728

  prep_w<<<dim3(576), dim3(256), 0, stream>>>(Wq, Wk, Wv, wfrag);
  qkv_gemm<<<dim3(1024), dim3(128), 0, stream>>>(x, wfrag, bq, bk, bv, qkv);
  vtrans<<<dim3(T_ / 64, B_), dim3(256), 0, stream>>>(qkv, vtb);
  flash<<<dim3(512), dim3(256), 0, stream>>>(qkv, vtb, out);
}

// Round 10
// 50.490 us; speedup vs baseline: 2.1951x; 1.0269x over previous
//
#include <hip/hip_runtime.h>
#include <hip/hip_bf16.h>
#include <math.h>

// Problem dims (fixed by reference)
#define B_ 16
#define T_ 1024
#define C_ 768
#define H_ 64

typedef __attribute__((ext_vector_type(8))) short bf16x8;
typedef __attribute__((ext_vector_type(4))) float f32x4;
typedef __attribute__((ext_vector_type(16))) float f32x16;

// fp32 -> bf16 (round-to-nearest-even)
__device__ __forceinline__ short f2bf(float f) {
  union { float f; unsigned u; } un;
  un.f = f;
  unsigned r = un.u + 0x7FFFu + ((un.u >> 16) & 1u);
  return (short)(r >> 16);
}

// ---------------------------------------------------------------------------
// Kernel 1: W prep in 32x32x16 MFMA fragment order.
// frag f = ks*6 + ct (ks = k-step of 16, 0..47; ct = 32-col group, 0..5).
// elem: wfrag[f*512 + l*8 + j] = W_mat[k][ncol], col = ct*32 + (l&31),
// mat = col>>6, ncol = col&63, k = ks*16 + (l>>5)*8 + j.
// ---------------------------------------------------------------------------
__global__ __launch_bounds__(256) void prep_w(
    const float* __restrict__ Wq, const float* __restrict__ Wk,
    const float* __restrict__ Wv, short* __restrict__ wfrag) {
  const int o = blockIdx.x * 256 + threadIdx.x;   // 0..147455
  const int j = o & 7;
  const int l = (o >> 3) & 63;
  const int f = o >> 9;                            // 0..287
  const int ct = f % 6;
  const int ks = f / 6;
  const int col = ct * 32 + (l & 31);
  const int mat = col >> 6;
  const int ncol = col & 63;
  const int k = ks * 16 + (l >> 5) * 8 + j;
  const float* W = (mat == 0) ? Wq : (mat == 1) ? Wk : Wv;
  wfrag[o] = f2bf(W[(size_t)k * H_ + ncol]);
}

// ---------------------------------------------------------------------------
// Kernel 2: QKV projection, 32x32x16 MFMA. Block = 256 thr = 4 waves, one
// 32-row tile; wave w = K-quarter (192 k = 3 chunks of BK=64). Each wave:
// 32 rows x 192 cols (6 x f32x16 acc). x staged per-wave via global_load_lds
// (4-bit XOR pre-swizzled source), double-buffered. W-frags from L2 (24
// coalesced 1KB loads/chunk -> 24 MFMA, 2x FLOP/load vs 16x16). Merge: two
// pool phases in the dead staging region (write w0/w1, read-add w2/w3).
// ---------------------------------------------------------------------------
#define QKV_LDSF 16384  // floats: 4 waves * 2 bufs * 2048 = 64 KB

__global__ __launch_bounds__(256, 2) void qkv_gemm(
    const float* __restrict__ x, const short* __restrict__ wfrag,
    const float* __restrict__ bq, const float* __restrict__ bk,
    const float* __restrict__ bv, short* __restrict__ qkv) {
  __shared__ float lds[QKV_LDSF];
  const int rt = blockIdx.x;            // 32-row tile
  const int tid = threadIdx.x;
  const int w  = tid >> 6;              // wave = K-quarter
  const int l  = tid & 63;
  const int lo5 = l & 31;               // MFMA row/col lane index
  const int hi1 = l >> 5;               // k-group within frag

  float* stg = lds + w * 4096;          // 2 bufs x 2048 floats (8KB each)
  const char* xb = (const char*)(x + (size_t)rt * 32 * C_ + w * 192);

  // stage chunk c (64 k-floats x 32 rows = 8KB): 8 global_load_lds.
  // LDS linear [row][256B]; source granule pre-swizzled with 4-bit XOR so
  // reads (row-major stride 256B) can swizzle conflict-free.
  auto STAGE = [&](int buf, int c) {
    #pragma unroll
    for (int s = 0; s < 8; ++s) {
      const int row = s * 4 + (l >> 4);
      const char* src = xb + (size_t)row * (C_ * 4) + (size_t)c * 256
                        + (((l & 15) ^ (row & 15)) << 4);
      float* dst = stg + buf * 2048 + s * 256;  // wave-uniform base
      __builtin_amdgcn_global_load_lds(
          (const __attribute__((address_space(1))) void*)src,
          (__attribute__((address_space(3))) void*)dst, 16, 0, 0);
    }
  };

  f32x16 acc[6];
  #pragma unroll
  for (int ct = 0; ct < 6; ++ct)
    #pragma unroll
    for (int r = 0; r < 16; ++r) acc[ct][r] = 0.f;

  STAGE(0, 0);

  #pragma unroll
  for (int c = 0; c < 3; ++c) {
    const int buf = c & 1;
    __builtin_amdgcn_sched_barrier(0);
    // ---- 24 W-frag loads for this chunk (ks = w*12 + c*4 + t, ct 0..5)
    bf16x8 wf[4][6];
    #pragma unroll
    for (int t = 0; t < 4; ++t)
      #pragma unroll
      for (int ct = 0; ct < 6; ++ct)
        wf[t][ct] = *(const bf16x8*)(wfrag
            + ((size_t)((w * 12 + c * 4 + t) * 6 + ct) << 9) + l * 8);
    __builtin_amdgcn_sched_barrier(0);
    // ---- stage next chunk (stays in flight across compute)
    if (c < 2) STAGE(buf ^ 1, c + 1);
    __builtin_amdgcn_sched_barrier(0);
    // ---- wait for THIS chunk's stage only (issued after S(c): 24 wf + 8 stage)
    if (c < 2) { asm volatile("s_waitcnt vmcnt(32)" ::: "memory"); }
    else       { asm volatile("s_waitcnt vmcnt(24)" ::: "memory"); }
    __builtin_amdgcn_sched_barrier(0);
    // ---- compute: per k-step t: A-frag from LDS (XOR-swz) + cvt + 6 MFMAs
    #pragma unroll
    for (int t = 0; t < 4; ++t) {
      const char* rb = (const char*)(stg + buf * 2048) + lo5 * 256;
      const int m = lo5 & 15;
      const int g0 = t * 4 + hi1 * 2;         // even granule
      f32x4 x0 = *(const f32x4*)(rb + (((g0)     ^ m) << 4));
      f32x4 x1 = *(const f32x4*)(rb + (((g0 + 1) ^ m) << 4));
      bf16x8 af;
      #pragma unroll
      for (int j = 0; j < 4; ++j) { af[j] = f2bf(x0[j]); af[4 + j] = f2bf(x1[j]); }
      __builtin_amdgcn_s_setprio(1);
      #pragma unroll
      for (int ct = 0; ct < 6; ++ct)
        acc[ct] = __builtin_amdgcn_mfma_f32_32x32x16_bf16(af, wf[t][ct], acc[ct], 0, 0, 0);
      __builtin_amdgcn_s_setprio(0);
    }
  }

  // ---- merge K-quarters: pool[2][32][200] f32 overlaps dead staging region
  __syncthreads();
  float* pool = lds;
  if (w < 2) {
    #pragma unroll
    for (int ct = 0; ct < 6; ++ct)
      #pragma unroll
      for (int r = 0; r < 16; ++r) {
        const int row = (r & 3) + 8 * (r >> 2) + 4 * hi1;
        pool[w * 6400 + row * 200 + ct * 32 + lo5] = acc[ct][r];
      }
  }
  __syncthreads();
  if (w >= 2) {
    #pragma unroll
    for (int ct = 0; ct < 6; ++ct)
      #pragma unroll
      for (int r = 0; r < 16; ++r) {
        const int row = (r & 3) + 8 * (r >> 2) + 4 * hi1;
        float* p = &pool[(w - 2) * 6400 + row * 200 + ct * 32 + lo5];
        *p += acc[ct][r];
      }
  }
  __syncthreads();

  // ---- epilogue: thread t -> row = t>>3 (0..31), cols (t&7)*24 .. +23
  {
    const int row = tid >> 3;
    const int c0 = (tid & 7) * 24;
    bf16x8 o0, o1, o2;
    #pragma unroll
    for (int j = 0; j < 24; ++j) {
      const int col = c0 + j;
      float s = pool[row * 200 + col] + pool[6400 + row * 200 + col];
      const int mat = col >> 6;
      const float* bb = (mat == 0) ? bq : (mat == 1) ? bk : bv;
      s += bb[col & 63];
      const short v = f2bf(s);
      if (j < 8) o0[j] = v; else if (j < 16) o1[j - 8] = v; else o2[j - 16] = v;
    }
    short* op = qkv + ((size_t)(rt * 32 + row)) * 192 + c0;
    *(bf16x8*)(op)      = o0;
    *(bf16x8*)(op + 8)  = o1;
    *(bf16x8*)(op + 16) = o2;
  }
}

// ---------------------------------------------------------------------------
// Kernel 3: V transpose — Vt[b][n][t] = v[b][t][n] (bf16), via LDS tiles.
// (unchanged; reads v at qkv[row][128..192), stride 192)
// ---------------------------------------------------------------------------
__global__ __launch_bounds__(256) void vtrans(const short* __restrict__ qkv,
                                              short* __restrict__ vt) {
  __shared__ short tile[64][66];
  const int b = blockIdx.y;
  const int tb = blockIdx.x * 64;
  const int tid = threadIdx.x;

  {
    const int tt = tid >> 2, c = (tid & 3) * 16;
    const short* src = qkv + (size_t)(b * T_ + tb + tt) * 192 + 128 + c;
    bf16x8 v0 = *(const bf16x8*)(src);
    bf16x8 v1 = *(const bf16x8*)(src + 8);
    #pragma unroll
    for (int j = 0; j < 8; ++j) { tile[tt][c + j] = v0[j]; tile[tt][c + 8 + j] = v1[j]; }
  }
  __syncthreads();
  {
    const int n = tid >> 2, toff = (tid & 3) * 16;
    short* dst = vt + ((size_t)(b * H_ + n)) * T_ + tb + toff;
    bf16x8 o0, o1;
    #pragma unroll
    for (int j = 0; j < 8; ++j) { o0[j] = tile[toff + j][n]; o1[j] = tile[toff + 8 + j][n]; }
    *(bf16x8*)(dst) = o0;
    *(bf16x8*)(dst + 8) = o1;
  }
}

// ---------------------------------------------------------------------------
// Kernel 4: flash attention — UNCHANGED from round 9 (paired q-tiles,
// 4-way KV-split, swapped QK^T, XCD-aware grid, defer-max).
// ---------------------------------------------------------------------------
#define SCALE_LOG2E 0.18033688011114382f  // 0.125 * log2(e)

__global__ __launch_bounds__(256) void flash(
    const short* __restrict__ qkv, const short* __restrict__ vt,
    float* __restrict__ out) {
  __shared__ __align__(16) short p_lds[4][2][16][72];
  __shared__ float o_sh[4][16][64];
  __shared__ float ml_sh[4][2][2][16];  // [wave][tile][m|l][row]

  const int wgid = blockIdx.x;
  const int kk = wgid >> 3;
  const int qp = 31 - (kk & 31);            // big pairs dispatched first
  const int b  = (wgid & 7) + 8 * (kk >> 5);

  const int w = threadIdx.x >> 6;
  const int l = threadIdx.x & 63;
  const int lo = l & 15, hi = l >> 4;
  const int off = hi * 4;

  const int qt0 = 2 * qp, qt1 = 2 * qp + 1;
  const int dtile = qt0 >> 2;
  const int ntot = dtile + 1;
  const int span = (ntot + 3) >> 2;
  const int kv0 = w * span;
  const int kv1 = min(ntot, kv0 + span);
  const int qr0 = qt0 & 3, qr1 = qr0 + 1;

  const short* qrowA = qkv + (size_t)(b * T_ + qt0 * 16 + lo) * 192;
  bf16x8 qA0 = *(const bf16x8*)(qrowA + hi * 8);
  bf16x8 qA1 = *(const bf16x8*)(qrowA + 32 + hi * 8);
  const short* qrowB = qkv + (size_t)(b * T_ + qt1 * 16 + lo) * 192;
  bf16x8 qB0 = *(const bf16x8*)(qrowB + hi * 8);
  bf16x8 qB1 = *(const bf16x8*)(qrowB + 32 + hi * 8);

  float mA = -1e30f, lsA = 0.f;
  float mB = -1e30f, lsB = 0.f;
  f32x4 oA[4], oB[4];
  #pragma unroll
  for (int dt = 0; dt < 4; ++dt) {
    oA[dt] = (f32x4){0.f, 0.f, 0.f, 0.f};
    oB[dt] = (f32x4){0.f, 0.f, 0.f, 0.f};
  }

  for (int kvt = kv0; kvt < kv1; ++kvt) {
    const bool diag = (kvt == dtile);
    const int nctA = diag ? (qr0 + 1) : 4;
    const int nctB = diag ? (qr1 + 1) : 4;

    bf16x8 kf[8], vf[8];
    #pragma unroll
    for (int ct = 0; ct < 4; ++ct) {
      const short* krow = qkv + (size_t)(b * T_ + kvt * 64 + ct * 16 + lo) * 192 + 64;
      kf[2 * ct]     = *(const bf16x8*)(krow + hi * 8);
      kf[2 * ct + 1] = *(const bf16x8*)(krow + 32 + hi * 8);
    }
    #pragma unroll
    for (int dt = 0; dt < 4; ++dt) {
      const short* vrow = vt + (size_t)(b * H_ + dt * 16 + lo) * T_ + kvt * 64;
      vf[2 * dt]     = *(const bf16x8*)(vrow + hi * 8);
      vf[2 * dt + 1] = *(const bf16x8*)(vrow + 32 + hi * 8);
    }

    f32x4 svA[4], svB[4];
    #pragma unroll
    for (int ct = 0; ct < 4; ++ct) {
      svA[ct] = (f32x4){0.f, 0.f, 0.f, 0.f};
      svB[ct] = (f32x4){0.f, 0.f, 0.f, 0.f};
    }
    __builtin_amdgcn_s_setprio(1);
    #pragma unroll
    for (int ct = 0; ct < 4; ++ct) {
      if (ct < nctA) {
        svA[ct] = __builtin_amdgcn_mfma_f32_16x16x32_bf16(kf[2 * ct], qA0, svA[ct], 0, 0, 0);
        svA[ct] = __builtin_amdgcn_mfma_f32_16x16x32_bf16(kf[2 * ct + 1], qA1, svA[ct], 0, 0, 0);
      }
      if (ct < nctB) {
        svB[ct] = __builtin_amdgcn_mfma_f32_16x16x32_bf16(kf[2 * ct], qB0, svB[ct], 0, 0, 0);
        svB[ct] = __builtin_amdgcn_mfma_f32_16x16x32_bf16(kf[2 * ct + 1], qB1, svB[ct], 0, 0, 0);
      }
    }
    __builtin_amdgcn_s_setprio(0);

    #pragma unroll
    for (int ct = 0; ct < 4; ++ct) {
      #pragma unroll
      for (int r = 0; r < 4; ++r) {
        float sA = (ct < nctA) ? svA[ct][r] * SCALE_LOG2E : -1e30f;
        if (diag && ct == qr0 && (off + r) > lo) sA = -1e30f;
        svA[ct][r] = sA;
        float sB = (ct < nctB) ? svB[ct][r] * SCALE_LOG2E : -1e30f;
        if (diag && ct == qr1 && (off + r) > lo) sB = -1e30f;
        svB[ct][r] = sB;
      }
    }

    {
      float tmax = svA[0][0];
      #pragma unroll
      for (int ct = 0; ct < 4; ++ct)
        #pragma unroll
        for (int r = 0; r < 4; ++r) tmax = fmaxf(tmax, svA[ct][r]);
      tmax = fmaxf(tmax, __shfl_xor(tmax, 16));
      tmax = fmaxf(tmax, __shfl_xor(tmax, 32));
      if (!__all(tmax - mA <= 8.0f)) {
        const float mn = fmaxf(mA, tmax);
        const float corr = exp2f(mA - mn);
        mA = mn;
        lsA *= corr;
        #pragma unroll
        for (int r = 0; r < 4; ++r) {
          const float cr = __shfl(corr, off + r);
          #pragma unroll
          for (int dt = 0; dt < 4; ++dt) oA[dt][r] *= cr;
        }
      }
      float psum = 0.f;
      #pragma unroll
      for (int ct = 0; ct < 4; ++ct) {
        #pragma unroll
        for (int r = 0; r < 4; ++r) {
          float p = exp2f(svA[ct][r] - mA);
          svA[ct][r] = p;
          psum += p;
        }
      }
      psum += __shfl_xor(psum, 16);
      psum += __shfl_xor(psum, 32);
      lsA += psum;
      #pragma unroll
      for (int ct = 0; ct < 4; ++ct) {
        __hip_bfloat162 p01 = __float22bfloat162_rn(float2{svA[ct][0], svA[ct][1]});
        __hip_bfloat162 p23 = __float22bfloat162_rn(float2{svA[ct][2], svA[ct][3]});
        uint2 pk;
        pk.x = *reinterpret_cast<unsigned*>(&p01);
        pk.y = *reinterpret_cast<unsigned*>(&p23);
        *reinterpret_cast<uint2*>(&p_lds[w][0][lo][ct * 16 + off]) = pk;
      }
    }
    {
      float tmax = svB[0][0];
      #pragma unroll
      for (int ct = 0; ct < 4; ++ct)
        #pragma unroll
        for (int r = 0; r < 4; ++r) tmax = fmaxf(tmax, svB[ct][r]);
      tmax = fmaxf(tmax, __shfl_xor(tmax, 16));
      tmax = fmaxf(tmax, __shfl_xor(tmax, 32));
      if (!__all(tmax - mB <= 8.0f)) {
        const float mn = fmaxf(mB, tmax);
        const float corr = exp2f(mB - mn);
        mB = mn;
        lsB *= corr;
        #pragma unroll
        for (int r = 0; r < 4; ++r) {
          const float cr = __shfl(corr, off + r);
          #pragma unroll
          for (int dt = 0; dt < 4; ++dt) oB[dt][r] *= cr;
        }
      }
      float psum = 0.f;
      #pragma unroll
      for (int ct = 0; ct < 4; ++ct) {
        #pragma unroll
        for (int r = 0; r < 4; ++r) {
          float p = exp2f(svB[ct][r] - mB);
          svB[ct][r] = p;
          psum += p;
        }
      }
      psum += __shfl_xor(psum, 16);
      psum += __shfl_xor(psum, 32);
      lsB += psum;
      #pragma unroll
      for (int ct = 0; ct < 4; ++ct) {
        __hip_bfloat162 p01 = __float22bfloat162_rn(float2{svB[ct][0], svB[ct][1]});
        __hip_bfloat162 p23 = __float22bfloat162_rn(float2{svB[ct][2], svB[ct][3]});
        uint2 pk;
        pk.x = *reinterpret_cast<unsigned*>(&p01);
        pk.y = *reinterpret_cast<unsigned*>(&p23);
        *reinterpret_cast<uint2*>(&p_lds[w][1][lo][ct * 16 + off]) = pk;
      }
    }

    bf16x8 paA0 = *(const bf16x8*)(&p_lds[w][0][lo][hi * 8]);
    bf16x8 paA1 = *(const bf16x8*)(&p_lds[w][0][lo][32 + hi * 8]);
    bf16x8 paB0 = *(const bf16x8*)(&p_lds[w][1][lo][hi * 8]);
    bf16x8 paB1 = *(const bf16x8*)(&p_lds[w][1][lo][32 + hi * 8]);
    __builtin_amdgcn_s_setprio(1);
    #pragma unroll
    for (int dt = 0; dt < 4; ++dt) {
      oA[dt] = __builtin_amdgcn_mfma_f32_16x16x32_bf16(paA0, vf[2 * dt], oA[dt], 0, 0, 0);
      oA[dt] = __builtin_amdgcn_mfma_f32_16x16x32_bf16(paA1, vf[2 * dt + 1], oA[dt], 0, 0, 0);
      oB[dt] = __builtin_amdgcn_mfma_f32_16x16x32_bf16(paB0, vf[2 * dt], oB[dt], 0, 0, 0);
      oB[dt] = __builtin_amdgcn_mfma_f32_16x16x32_bf16(paB1, vf[2 * dt + 1], oB[dt], 0, 0, 0);
    }
    __builtin_amdgcn_s_setprio(0);
  }

  if (hi == 0) {
    ml_sh[w][0][0][lo] = mA;  ml_sh[w][0][1][lo] = lsA;
    ml_sh[w][1][0][lo] = mB;  ml_sh[w][1][1][lo] = lsB;
  }

  #pragma unroll
  for (int dt = 0; dt < 4; ++dt)
    #pragma unroll
    for (int r = 0; r < 4; ++r)
      o_sh[w][off + r][dt * 16 + lo] = oA[dt][r];
  __syncthreads();
  {
    const int row = threadIdx.x >> 4;
    const int c0 = (threadIdx.x & 15) * 4;
    float M = fmaxf(fmaxf(ml_sh[0][0][0][row], ml_sh[1][0][0][row]),
                    fmaxf(ml_sh[2][0][0][row], ml_sh[3][0][0][row]));
    float e[4];
    float L = 0.f;
    #pragma unroll
    for (int w2 = 0; w2 < 4; ++w2) {
      e[w2] = exp2f(ml_sh[w2][0][0][row] - M);
      L += ml_sh[w2][0][1][row] * e[w2];
    }
    f32x4 o;
    #pragma unroll
    for (int j = 0; j < 4; ++j) {
      float O = 0.f;
      #pragma unroll
      for (int w2 = 0; w2 < 4; ++w2) O += e[w2] * o_sh[w2][row][c0 + j];
      o[j] = O / L;
    }
    *(f32x4*)(out + (size_t)(b * T_ + qt0 * 16 + row) * H_ + c0) = o;
  }
  __syncthreads();
  #pragma unroll
  for (int dt = 0; dt < 4; ++dt)
    #pragma unroll
    for (int r = 0; r < 4; ++r)
      o_sh[w][off + r][dt * 16 + lo] = oB[dt][r];
  __syncthreads();
  {
    const int row = threadIdx.x >> 4;
    const int c0 = (threadIdx.x & 15) * 4;
    float M = fmaxf(fmaxf(ml_sh[0][1][0][row], ml_sh[1][1][0][row]),
                    fmaxf(ml_sh[2][1][0][row], ml_sh[3][1][0][row]));
    float e[4];
    float L = 0.f;
    #pragma unroll
    for (int w2 = 0; w2 < 4; ++w2) {
      e[w2] = exp2f(ml_sh[w2][1][0][row] - M);
      L += ml_sh[w2][1][1][row] * e[w2];
    }
    f32x4 o;
    #pragma unroll
    for (int j = 0; j < 4; ++j) {
      float O = 0.f;
      #pragma unroll
      for (int w2 = 0; w2 < 4; ++w2) O += e[w2] * o_sh[w2][row][c0 + j];
      o[j] = O / L;
    }
    *(f32x4*)(out + (size_t)(b * T_ + qt1 * 16 + row) * H_ + c0) = o;
  }
}

// ---------------------------------------------------------------------------
extern "C" void kernel_launch(void* const* d_in, const int* in_sizes, int n_in,
                              void* d_out, int out_size, void* d_ws, size_t ws_size,
                              hipStream_t stream) {
  const float* x  = (const float*)d_in[0];
  const float* Wq = (const float*)d_in[1];
  const float* bq = (const float*)d_in[2];
  const float* Wk = (const float*)d_in[3];
  const float* bk = (const float*)d_in[4];
  const float* Wv = (const float*)d_in[5];
  const float* bv = (const float*)d_in[6];
  float* out = (float*)d_out;

  // workspace layout (shorts): wfrag | qkv(interleaved, stride 192) | vt
  short* wfrag = (short*)d_ws;
  short* qkv = wfrag + (size_t)3 * H_ * C_;          // 147456
  short* vtb = qkv + (size_t)B_ * T_ * 192;          // +3145728

  prep_w<<<dim3(576), dim3(256), 0, stream>>>(Wq, Wk, Wv, wfrag);
  qkv_gemm<<<dim3(512), dim3(256), 0, stream>>>(x, wfrag, bq, bk, bv, qkv);
  vtrans<<<dim3(T_ / 64, B_), dim3(256), 0, stream>>>(qkv, vtb);
  flash<<<dim3(512), dim3(256), 0, stream>>>(qkv, vtb, out);
}

// Round 11
// 45.506 us; speedup vs baseline: 2.4355x; 1.1095x over previous
//
#include <hip/hip_runtime.h>
#include <hip/hip_bf16.h>
#include <math.h>

// Problem dims (fixed by reference)
#define B_ 16
#define T_ 1024
#define C_ 768
#define H_ 64

typedef __attribute__((ext_vector_type(8))) short bf16x8;
typedef __attribute__((ext_vector_type(4))) float f32x4;
typedef __attribute__((ext_vector_type(16))) float f32x16;

// fp32 -> bf16 (round-to-nearest-even)
__device__ __forceinline__ short f2bf(float f) {
  union { float f; unsigned u; } un;
  un.f = f;
  unsigned r = un.u + 0x7FFFu + ((un.u >> 16) & 1u);
  return (short)(r >> 16);
}

// ---------------------------------------------------------------------------
// Kernel 1: W prep in 32x32x16 MFMA fragment order (unchanged from round 10).
// ---------------------------------------------------------------------------
__global__ __launch_bounds__(256) void prep_w(
    const float* __restrict__ Wq, const float* __restrict__ Wk,
    const float* __restrict__ Wv, short* __restrict__ wfrag) {
  const int o = blockIdx.x * 256 + threadIdx.x;   // 0..147455
  const int j = o & 7;
  const int l = (o >> 3) & 63;
  const int f = o >> 9;                            // 0..287
  const int ct = f % 6;
  const int ks = f / 6;
  const int col = ct * 32 + (l & 31);
  const int mat = col >> 6;
  const int ncol = col & 63;
  const int k = ks * 16 + (l >> 5) * 8 + j;
  const float* W = (mat == 0) ? Wq : (mat == 1) ? Wk : Wv;
  wfrag[o] = f2bf(W[(size_t)k * H_ + ncol]);
}

// ---------------------------------------------------------------------------
// Kernel 2: QKV projection, 32x32x16 MFMA (round-10 structure) + FUSED
// V-transpose epilogue. Outputs: qk[row][128] (q|k, stride 128) and
// vt[b][n][t] (V transposed, bf16x8 contiguous stores).
// ---------------------------------------------------------------------------
#define QKV_LDSF 16384  // floats: 4 waves * 2 bufs * 2048 = 64 KB

__global__ __launch_bounds__(256, 2) void qkv_gemm(
    const float* __restrict__ x, const short* __restrict__ wfrag,
    const float* __restrict__ bq, const float* __restrict__ bk,
    const float* __restrict__ bv,
    short* __restrict__ qk, short* __restrict__ vt) {
  __shared__ float lds[QKV_LDSF];
  const int rt = blockIdx.x;            // 32-row tile
  const int tid = threadIdx.x;
  const int w  = tid >> 6;              // wave = K-quarter
  const int l  = tid & 63;
  const int lo5 = l & 31;               // MFMA row/col lane index
  const int hi1 = l >> 5;               // k-group within frag

  float* stg = lds + w * 4096;          // 2 bufs x 2048 floats (8KB each)
  const char* xb = (const char*)(x + (size_t)rt * 32 * C_ + w * 192);

  auto STAGE = [&](int buf, int c) {
    #pragma unroll
    for (int s = 0; s < 8; ++s) {
      const int row = s * 4 + (l >> 4);
      const char* src = xb + (size_t)row * (C_ * 4) + (size_t)c * 256
                        + (((l & 15) ^ (row & 15)) << 4);
      float* dst = stg + buf * 2048 + s * 256;  // wave-uniform base
      __builtin_amdgcn_global_load_lds(
          (const __attribute__((address_space(1))) void*)src,
          (__attribute__((address_space(3))) void*)dst, 16, 0, 0);
    }
  };

  f32x16 acc[6];
  #pragma unroll
  for (int ct = 0; ct < 6; ++ct)
    #pragma unroll
    for (int r = 0; r < 16; ++r) acc[ct][r] = 0.f;

  STAGE(0, 0);

  #pragma unroll
  for (int c = 0; c < 3; ++c) {
    const int buf = c & 1;
    __builtin_amdgcn_sched_barrier(0);
    // ---- 24 W-frag loads for this chunk
    bf16x8 wf[4][6];
    #pragma unroll
    for (int t = 0; t < 4; ++t)
      #pragma unroll
      for (int ct = 0; ct < 6; ++ct)
        wf[t][ct] = *(const bf16x8*)(wfrag
            + ((size_t)((w * 12 + c * 4 + t) * 6 + ct) << 9) + l * 8);
    __builtin_amdgcn_sched_barrier(0);
    // ---- stage next chunk
    if (c < 2) STAGE(buf ^ 1, c + 1);
    __builtin_amdgcn_sched_barrier(0);
    // ---- wait for THIS chunk's stage only
    if (c < 2) { asm volatile("s_waitcnt vmcnt(32)" ::: "memory"); }
    else       { asm volatile("s_waitcnt vmcnt(24)" ::: "memory"); }
    __builtin_amdgcn_sched_barrier(0);
    // ---- compute: per k-step t: A-frag from LDS (XOR-swz) + cvt + 6 MFMAs
    #pragma unroll
    for (int t = 0; t < 4; ++t) {
      const char* rb = (const char*)(stg + buf * 2048) + lo5 * 256;
      const int m = lo5 & 15;
      const int g0 = t * 4 + hi1 * 2;
      f32x4 x0 = *(const f32x4*)(rb + (((g0)     ^ m) << 4));
      f32x4 x1 = *(const f32x4*)(rb + (((g0 + 1) ^ m) << 4));
      bf16x8 af;
      #pragma unroll
      for (int j = 0; j < 4; ++j) { af[j] = f2bf(x0[j]); af[4 + j] = f2bf(x1[j]); }
      __builtin_amdgcn_s_setprio(1);
      #pragma unroll
      for (int ct = 0; ct < 6; ++ct)
        acc[ct] = __builtin_amdgcn_mfma_f32_32x32x16_bf16(af, wf[t][ct], acc[ct], 0, 0, 0);
      __builtin_amdgcn_s_setprio(0);
    }
  }

  // ---- merge K-quarters: pool[2][32][200] f32 overlaps dead staging region
  __syncthreads();
  float* pool = lds;
  if (w < 2) {
    #pragma unroll
    for (int ct = 0; ct < 6; ++ct)
      #pragma unroll
      for (int r = 0; r < 16; ++r) {
        const int row = (r & 3) + 8 * (r >> 2) + 4 * hi1;
        pool[w * 6400 + row * 200 + ct * 32 + lo5] = acc[ct][r];
      }
  }
  __syncthreads();
  if (w >= 2) {
    #pragma unroll
    for (int ct = 0; ct < 6; ++ct)
      #pragma unroll
      for (int r = 0; r < 16; ++r) {
        const int row = (r & 3) + 8 * (r >> 2) + 4 * hi1;
        float* p = &pool[(w - 2) * 6400 + row * 200 + ct * 32 + lo5];
        *p += acc[ct][r];
      }
  }
  __syncthreads();

  // ---- epilogue A: qk (cols 0..127, stride 128). thread -> row=tid>>3,
  // cols (tid&7)*16 .. +15.
  {
    const int row = tid >> 3;
    const int c0 = (tid & 7) * 16;
    bf16x8 o0, o1;
    #pragma unroll
    for (int j = 0; j < 16; ++j) {
      const int col = c0 + j;
      float s = pool[row * 200 + col] + pool[6400 + row * 200 + col];
      s += (col < 64) ? bq[col] : bk[col - 64];
      const short v = f2bf(s);
      if (j < 8) o0[j] = v; else o1[j - 8] = v;
    }
    short* op = qk + ((size_t)(rt * 32 + row)) * 128 + c0;
    *(bf16x8*)(op)     = o0;
    *(bf16x8*)(op + 8) = o1;
  }
  // ---- epilogue B: fused V-transpose. thread -> n=tid>>2 (0..63),
  // sub=tid&3 -> rows sub*8..+7; contiguous bf16x8 store to vt.
  {
    const int n = tid >> 2;
    const int sub = tid & 3;
    const int b = rt >> 5;
    const int tloc = (rt & 31) * 32;
    const float bias_v = bv[n];
    bf16x8 o;
    #pragma unroll
    for (int j = 0; j < 8; ++j) {
      const int row = sub * 8 + j;
      float s = pool[row * 200 + 128 + n] + pool[6400 + row * 200 + 128 + n];
      o[j] = f2bf(s + bias_v);
    }
    *(bf16x8*)(vt + ((size_t)(b * H_ + n)) * T_ + tloc + sub * 8) = o;
  }
}

// ---------------------------------------------------------------------------
// Kernel 3: flash attention — round-9/10 structure (paired q-tiles, 4-way
// KV-split, swapped QK^T, XCD-aware grid, defer-max); qk stride 128, k at +64.
// ---------------------------------------------------------------------------
#define SCALE_LOG2E 0.18033688011114382f  // 0.125 * log2(e)

__global__ __launch_bounds__(256) void flash(
    const short* __restrict__ qk, const short* __restrict__ vt,
    float* __restrict__ out) {
  __shared__ __align__(16) short p_lds[4][2][16][72];
  __shared__ float o_sh[4][16][64];
  __shared__ float ml_sh[4][2][2][16];  // [wave][tile][m|l][row]

  const int wgid = blockIdx.x;
  const int kk = wgid >> 3;
  const int qp = 31 - (kk & 31);            // big pairs dispatched first
  const int b  = (wgid & 7) + 8 * (kk >> 5);

  const int w = threadIdx.x >> 6;
  const int l = threadIdx.x & 63;
  const int lo = l & 15, hi = l >> 4;
  const int off = hi * 4;

  const int qt0 = 2 * qp, qt1 = 2 * qp + 1;
  const int dtile = qt0 >> 2;
  const int ntot = dtile + 1;
  const int span = (ntot + 3) >> 2;
  const int kv0 = w * span;
  const int kv1 = min(ntot, kv0 + span);
  const int qr0 = qt0 & 3, qr1 = qr0 + 1;

  const short* qrowA = qk + (size_t)(b * T_ + qt0 * 16 + lo) * 128;
  bf16x8 qA0 = *(const bf16x8*)(qrowA + hi * 8);
  bf16x8 qA1 = *(const bf16x8*)(qrowA + 32 + hi * 8);
  const short* qrowB = qk + (size_t)(b * T_ + qt1 * 16 + lo) * 128;
  bf16x8 qB0 = *(const bf16x8*)(qrowB + hi * 8);
  bf16x8 qB1 = *(const bf16x8*)(qrowB + 32 + hi * 8);

  float mA = -1e30f, lsA = 0.f;
  float mB = -1e30f, lsB = 0.f;
  f32x4 oA[4], oB[4];
  #pragma unroll
  for (int dt = 0; dt < 4; ++dt) {
    oA[dt] = (f32x4){0.f, 0.f, 0.f, 0.f};
    oB[dt] = (f32x4){0.f, 0.f, 0.f, 0.f};
  }

  for (int kvt = kv0; kvt < kv1; ++kvt) {
    const bool diag = (kvt == dtile);
    const int nctA = diag ? (qr0 + 1) : 4;
    const int nctB = diag ? (qr1 + 1) : 4;

    bf16x8 kf[8], vf[8];
    #pragma unroll
    for (int ct = 0; ct < 4; ++ct) {
      const short* krow = qk + (size_t)(b * T_ + kvt * 64 + ct * 16 + lo) * 128 + 64;
      kf[2 * ct]     = *(const bf16x8*)(krow + hi * 8);
      kf[2 * ct + 1] = *(const bf16x8*)(krow + 32 + hi * 8);
    }
    #pragma unroll
    for (int dt = 0; dt < 4; ++dt) {
      const short* vrow = vt + (size_t)(b * H_ + dt * 16 + lo) * T_ + kvt * 64;
      vf[2 * dt]     = *(const bf16x8*)(vrow + hi * 8);
      vf[2 * dt + 1] = *(const bf16x8*)(vrow + 32 + hi * 8);
    }

    f32x4 svA[4], svB[4];
    #pragma unroll
    for (int ct = 0; ct < 4; ++ct) {
      svA[ct] = (f32x4){0.f, 0.f, 0.f, 0.f};
      svB[ct] = (f32x4){0.f, 0.f, 0.f, 0.f};
    }
    __builtin_amdgcn_s_setprio(1);
    #pragma unroll
    for (int ct = 0; ct < 4; ++ct) {
      if (ct < nctA) {
        svA[ct] = __builtin_amdgcn_mfma_f32_16x16x32_bf16(kf[2 * ct], qA0, svA[ct], 0, 0, 0);
        svA[ct] = __builtin_amdgcn_mfma_f32_16x16x32_bf16(kf[2 * ct + 1], qA1, svA[ct], 0, 0, 0);
      }
      if (ct < nctB) {
        svB[ct] = __builtin_amdgcn_mfma_f32_16x16x32_bf16(kf[2 * ct], qB0, svB[ct], 0, 0, 0);
        svB[ct] = __builtin_amdgcn_mfma_f32_16x16x32_bf16(kf[2 * ct + 1], qB1, svB[ct], 0, 0, 0);
      }
    }
    __builtin_amdgcn_s_setprio(0);

    #pragma unroll
    for (int ct = 0; ct < 4; ++ct) {
      #pragma unroll
      for (int r = 0; r < 4; ++r) {
        float sA = (ct < nctA) ? svA[ct][r] * SCALE_LOG2E : -1e30f;
        if (diag && ct == qr0 && (off + r) > lo) sA = -1e30f;
        svA[ct][r] = sA;
        float sB = (ct < nctB) ? svB[ct][r] * SCALE_LOG2E : -1e30f;
        if (diag && ct == qr1 && (off + r) > lo) sB = -1e30f;
        svB[ct][r] = sB;
      }
    }

    {
      float tmax = svA[0][0];
      #pragma unroll
      for (int ct = 0; ct < 4; ++ct)
        #pragma unroll
        for (int r = 0; r < 4; ++r) tmax = fmaxf(tmax, svA[ct][r]);
      tmax = fmaxf(tmax, __shfl_xor(tmax, 16));
      tmax = fmaxf(tmax, __shfl_xor(tmax, 32));
      if (!__all(tmax - mA <= 8.0f)) {
        const float mn = fmaxf(mA, tmax);
        const float corr = exp2f(mA - mn);
        mA = mn;
        lsA *= corr;
        #pragma unroll
        for (int r = 0; r < 4; ++r) {
          const float cr = __shfl(corr, off + r);
          #pragma unroll
          for (int dt = 0; dt < 4; ++dt) oA[dt][r] *= cr;
        }
      }
      float psum = 0.f;
      #pragma unroll
      for (int ct = 0; ct < 4; ++ct) {
        #pragma unroll
        for (int r = 0; r < 4; ++r) {
          float p = exp2f(svA[ct][r] - mA);
          svA[ct][r] = p;
          psum += p;
        }
      }
      psum += __shfl_xor(psum, 16);
      psum += __shfl_xor(psum, 32);
      lsA += psum;
      #pragma unroll
      for (int ct = 0; ct < 4; ++ct) {
        __hip_bfloat162 p01 = __float22bfloat162_rn(float2{svA[ct][0], svA[ct][1]});
        __hip_bfloat162 p23 = __float22bfloat162_rn(float2{svA[ct][2], svA[ct][3]});
        uint2 pk;
        pk.x = *reinterpret_cast<unsigned*>(&p01);
        pk.y = *reinterpret_cast<unsigned*>(&p23);
        *reinterpret_cast<uint2*>(&p_lds[w][0][lo][ct * 16 + off]) = pk;
      }
    }
    {
      float tmax = svB[0][0];
      #pragma unroll
      for (int ct = 0; ct < 4; ++ct)
        #pragma unroll
        for (int r = 0; r < 4; ++r) tmax = fmaxf(tmax, svB[ct][r]);
      tmax = fmaxf(tmax, __shfl_xor(tmax, 16));
      tmax = fmaxf(tmax, __shfl_xor(tmax, 32));
      if (!__all(tmax - mB <= 8.0f)) {
        const float mn = fmaxf(mB, tmax);
        const float corr = exp2f(mB - mn);
        mB = mn;
        lsB *= corr;
        #pragma unroll
        for (int r = 0; r < 4; ++r) {
          const float cr = __shfl(corr, off + r);
          #pragma unroll
          for (int dt = 0; dt < 4; ++dt) oB[dt][r] *= cr;
        }
      }
      float psum = 0.f;
      #pragma unroll
      for (int ct = 0; ct < 4; ++ct) {
        #pragma unroll
        for (int r = 0; r < 4; ++r) {
          float p = exp2f(svB[ct][r] - mB);
          svB[ct][r] = p;
          psum += p;
        }
      }
      psum += __shfl_xor(psum, 16);
      psum += __shfl_xor(psum, 32);
      lsB += psum;
      #pragma unroll
      for (int ct = 0; ct < 4; ++ct) {
        __hip_bfloat162 p01 = __float22bfloat162_rn(float2{svB[ct][0], svB[ct][1]});
        __hip_bfloat162 p23 = __float22bfloat162_rn(float2{svB[ct][2], svB[ct][3]});
        uint2 pk;
        pk.x = *reinterpret_cast<unsigned*>(&p01);
        pk.y = *reinterpret_cast<unsigned*>(&p23);
        *reinterpret_cast<uint2*>(&p_lds[w][1][lo][ct * 16 + off]) = pk;
      }
    }

    bf16x8 paA0 = *(const bf16x8*)(&p_lds[w][0][lo][hi * 8]);
    bf16x8 paA1 = *(const bf16x8*)(&p_lds[w][0][lo][32 + hi * 8]);
    bf16x8 paB0 = *(const bf16x8*)(&p_lds[w][1][lo][hi * 8]);
    bf16x8 paB1 = *(const bf16x8*)(&p_lds[w][1][lo][32 + hi * 8]);
    __builtin_amdgcn_s_setprio(1);
    #pragma unroll
    for (int dt = 0; dt < 4; ++dt) {
      oA[dt] = __builtin_amdgcn_mfma_f32_16x16x32_bf16(paA0, vf[2 * dt], oA[dt], 0, 0, 0);
      oA[dt] = __builtin_amdgcn_mfma_f32_16x16x32_bf16(paA1, vf[2 * dt + 1], oA[dt], 0, 0, 0);
      oB[dt] = __builtin_amdgcn_mfma_f32_16x16x32_bf16(paB0, vf[2 * dt], oB[dt], 0, 0, 0);
      oB[dt] = __builtin_amdgcn_mfma_f32_16x16x32_bf16(paB1, vf[2 * dt + 1], oB[dt], 0, 0, 0);
    }
    __builtin_amdgcn_s_setprio(0);
  }

  if (hi == 0) {
    ml_sh[w][0][0][lo] = mA;  ml_sh[w][0][1][lo] = lsA;
    ml_sh[w][1][0][lo] = mB;  ml_sh[w][1][1][lo] = lsB;
  }

  #pragma unroll
  for (int dt = 0; dt < 4; ++dt)
    #pragma unroll
    for (int r = 0; r < 4; ++r)
      o_sh[w][off + r][dt * 16 + lo] = oA[dt][r];
  __syncthreads();
  {
    const int row = threadIdx.x >> 4;
    const int c0 = (threadIdx.x & 15) * 4;
    float M = fmaxf(fmaxf(ml_sh[0][0][0][row], ml_sh[1][0][0][row]),
                    fmaxf(ml_sh[2][0][0][row], ml_sh[3][0][0][row]));
    float e[4];
    float L = 0.f;
    #pragma unroll
    for (int w2 = 0; w2 < 4; ++w2) {
      e[w2] = exp2f(ml_sh[w2][0][0][row] - M);
      L += ml_sh[w2][0][1][row] * e[w2];
    }
    f32x4 o;
    #pragma unroll
    for (int j = 0; j < 4; ++j) {
      float O = 0.f;
      #pragma unroll
      for (int w2 = 0; w2 < 4; ++w2) O += e[w2] * o_sh[w2][row][c0 + j];
      o[j] = O / L;
    }
    *(f32x4*)(out + (size_t)(b * T_ + qt0 * 16 + row) * H_ + c0) = o;
  }
  __syncthreads();
  #pragma unroll
  for (int dt = 0; dt < 4; ++dt)
    #pragma unroll
    for (int r = 0; r < 4; ++r)
      o_sh[w][off + r][dt * 16 + lo] = oB[dt][r];
  __syncthreads();
  {
    const int row = threadIdx.x >> 4;
    const int c0 = (threadIdx.x & 15) * 4;
    float M = fmaxf(fmaxf(ml_sh[0][1][0][row], ml_sh[1][1][0][row]),
                    fmaxf(ml_sh[2][1][0][row], ml_sh[3][1][0][row]));
    float e[4];
    float L = 0.f;
    #pragma unroll
    for (int w2 = 0; w2 < 4; ++w2) {
      e[w2] = exp2f(ml_sh[w2][1][0][row] - M);
      L += ml_sh[w2][1][1][row] * e[w2];
    }
    f32x4 o;
    #pragma unroll
    for (int j = 0; j < 4; ++j) {
      float O = 0.f;
      #pragma unroll
      for (int w2 = 0; w2 < 4; ++w2) O += e[w2] * o_sh[w2][row][c0 + j];
      o[j] = O / L;
    }
    *(f32x4*)(out + (size_t)(b * T_ + qt1 * 16 + row) * H_ + c0) = o;
  }
}

// ---------------------------------------------------------------------------
extern "C" void kernel_launch(void* const* d_in, const int* in_sizes, int n_in,
                              void* d_out, int out_size, void* d_ws, size_t ws_size,
                              hipStream_t stream) {
  const float* x  = (const float*)d_in[0];
  const float* Wq = (const float*)d_in[1];
  const float* bq = (const float*)d_in[2];
  const float* Wk = (const float*)d_in[3];
  const float* bk = (const float*)d_in[4];
  const float* Wv = (const float*)d_in[5];
  const float* bv = (const float*)d_in[6];
  float* out = (float*)d_out;

  // workspace layout (shorts): wfrag | qk (stride 128) | vt
  short* wfrag = (short*)d_ws;
  short* qk = wfrag + (size_t)3 * H_ * C_;           // 147456
  short* vtb = qk + (size_t)B_ * T_ * 128;           // +2097152

  prep_w<<<dim3(576), dim3(256), 0, stream>>>(Wq, Wk, Wv, wfrag);
  qkv_gemm<<<dim3(512), dim3(256), 0, stream>>>(x, wfrag, bq, bk, bv, qk, vtb);
  flash<<<dim3(512), dim3(256), 0, stream>>>(qk, vtb, out);
}